// Round 22
// baseline (121.595 us; speedup 1.0000x reference)
//
#include <hip/hip_runtime.h>
#include <hip/hip_fp16.h>

// out[m][n] = fp16( fp16( (sum_k x[m][k]*w6[n][k]) * scale[n] ) + bias[n] ), stored fp32
// v20: v18 gemm (128x128, 4 waves, 64x64 wave tile, BK=32, DMA double-buffer, counted
// vmcnt, raw barriers, XOR swizzle, fp16 partials) + FUSED finalize: per-output-tile
// atomic completion counters; the 8th sp-block to finish a tile sums the 8 fp16
// partial slices (same-XCD L2-hot by swizzle construction) and writes O with the
// reference's double rounding. Removes the finalize kernel + launch gap.

typedef __attribute__((ext_vector_type(8))) _Float16 half8;
typedef __attribute__((ext_vector_type(4))) _Float16 half4;
typedef __attribute__((ext_vector_type(2))) __fp16 fp16x2;   // cvt_pkrtz return type
typedef __attribute__((ext_vector_type(4))) float f32x4;

typedef const __attribute__((address_space(1))) void* gptr_t;
typedef __attribute__((address_space(3))) void* lptr_t;

constexpr int K = 4096, N = 4096, M = 256;
constexpr int BM = 128, BN = 128, BK = 32;
constexpr int SPL = 8;
constexpr int KSPL = K / SPL;     // 512
constexpr int NT = KSPL / BK;     // 16 phases

__device__ __forceinline__ void gload16(const void* g, void* l) {
    __builtin_amdgcn_global_load_lds((gptr_t)g, (lptr_t)l, 16, 0, 0);
}

__device__ __forceinline__ half8 cvt8(float4 f0, float4 f1) {   // exact: fp16-exact data
    fp16x2 p0 = __builtin_amdgcn_cvt_pkrtz(f0.x, f0.y);
    fp16x2 p1 = __builtin_amdgcn_cvt_pkrtz(f0.z, f0.w);
    fp16x2 p2 = __builtin_amdgcn_cvt_pkrtz(f1.x, f1.y);
    fp16x2 p3 = __builtin_amdgcn_cvt_pkrtz(f1.z, f1.w);
    half8 h;
    h[0]=(_Float16)p0[0]; h[1]=(_Float16)p0[1];
    h[2]=(_Float16)p1[0]; h[3]=(_Float16)p1[1];
    h[4]=(_Float16)p2[0]; h[5]=(_Float16)p2[1];
    h[6]=(_Float16)p3[0]; h[7]=(_Float16)p3[1];
    return h;
}

__global__ __launch_bounds__(256, 2)
void gemm(const float* __restrict__ X,
          const float* __restrict__ W,
          const float* __restrict__ S,
          const float* __restrict__ Bi,
          float* __restrict__ O,
          _Float16* __restrict__ P,     // [SPL][M][N] fp16 partials
          int* __restrict__ cnt)        // [64] per-output-tile counters (pre-zeroed)
{
    __shared__ __align__(16) float LA[2][BM * BK];   // 2 x 16 KB (X fp32)
    __shared__ __align__(16) float LB[2][BN * BK];   // 2 x 16 KB (W fp32)
    __shared__ int isWinner;

    const int tid = (int)threadIdx.x;
    const int l   = tid & 63;
    const int wv  = tid >> 6;           // 4 waves: 2(M) x 2(N), wave tile 64x64
    const int lc  = l & 15;
    const int lr  = l >> 4;
    const int wm  = (wv & 1) * 64;
    const int wn  = (wv >> 1) * 64;

    // XCD map: all 8 sp-blocks of a given (mb, nbl) share one XCD (sp lives in the
    // same-xcd index bits) -> winner reads partials from its own XCD's L2.
    const int bid = (int)blockIdx.x;
    const int xcd = bid & 7;
    const int i   = bid >> 3;           // 0..63
    const int mb  = i & 1;
    const int sp  = (i >> 1) & 7;
    const int nbl = i >> 4;             // 0..3
    const int bm  = mb * BM;
    const int bn  = (xcd * 4 + nbl) * BN;
    const int kb  = sp * KSPL;
    const int tileId = mb * 32 + (bn >> 7);   // 64 output tiles

    // ---- DMA staging (identical geometry for A and W; source pre-XOR-swizzled) ----
    const int srow = wv * 32 + (l >> 3);             // +8 per inst
    const int scho = ((l & 7) ^ (l >> 3)) * 4;       // floats
    const float* ag0 = X + (size_t)(bm + srow)      * K + kb + scho;
    const float* ag1 = X + (size_t)(bm + srow + 8)  * K + kb + scho;
    const float* ag2 = X + (size_t)(bm + srow + 16) * K + kb + scho;
    const float* ag3 = X + (size_t)(bm + srow + 24) * K + kb + scho;
    const float* wg0 = W + (size_t)(bn + srow)      * K + kb + scho;
    const float* wg1 = W + (size_t)(bn + srow + 8)  * K + kb + scho;
    const float* wg2 = W + (size_t)(bn + srow + 16) * K + kb + scho;
    const float* wg3 = W + (size_t)(bn + srow + 24) * K + kb + scho;
    const int sl0 = (wv * 32 + 0)  * BK;
    const int sl1 = (wv * 32 + 8)  * BK;
    const int sl2 = (wv * 32 + 16) * BK;
    const int sl3 = (wv * 32 + 24) * BK;

#define STAGE(t, bf) do {                                               \
        gload16(ag0 + (size_t)(t) * BK, &LA[bf][sl0]);                  \
        gload16(ag1 + (size_t)(t) * BK, &LA[bf][sl1]);                  \
        gload16(ag2 + (size_t)(t) * BK, &LA[bf][sl2]);                  \
        gload16(ag3 + (size_t)(t) * BK, &LA[bf][sl3]);                  \
        gload16(wg0 + (size_t)(t) * BK, &LB[bf][sl0]);                  \
        gload16(wg1 + (size_t)(t) * BK, &LB[bf][sl1]);                  \
        gload16(wg2 + (size_t)(t) * BK, &LB[bf][sl2]);                  \
        gload16(wg3 + (size_t)(t) * BK, &LB[bf][sl3]);                  \
    } while (0)   // exactly 8 vmem ops per wave per tile

    // frag read offsets (row&7 == lc&7; fp32 chunk pair {2lr,2lr+1} stored XOR lc&7)
    const int sz0 = (((lr << 1))     ^ (lc & 7)) << 2;
    const int sz1 = (((lr << 1) | 1) ^ (lc & 7)) << 2;

    f32x4 acc[4][4];
    #pragma unroll
    for (int a = 0; a < 4; ++a)
        #pragma unroll
        for (int b = 0; b < 4; ++b)
            acc[a][b] = (f32x4){0.f, 0.f, 0.f, 0.f};

#define COMPUTE(bf) do {                                                \
        half8 af[4];                                                    \
        _Pragma("unroll")                                               \
        for (int ar = 0; ar < 4; ++ar) {                                \
            const float* pa = &LA[bf][(wm + ar * 16 + lc) * BK];        \
            af[ar] = cvt8(*(const float4*)(pa + sz0),                   \
                          *(const float4*)(pa + sz1));                  \
        }                                                               \
        _Pragma("unroll")                                               \
        for (int br = 0; br < 4; ++br) {                                \
            const float* pw = &LB[bf][(wn + br * 16 + lc) * BK];        \
            half8 bb = cvt8(*(const float4*)(pw + sz0),                 \
                            *(const float4*)(pw + sz1));                \
            acc[0][br] = __builtin_amdgcn_mfma_f32_16x16x32_f16(af[0], bb, acc[0][br], 0, 0, 0); \
            acc[1][br] = __builtin_amdgcn_mfma_f32_16x16x32_f16(af[1], bb, acc[1][br], 0, 0, 0); \
            acc[2][br] = __builtin_amdgcn_mfma_f32_16x16x32_f16(af[2], bb, acc[2][br], 0, 0, 0); \
            acc[3][br] = __builtin_amdgcn_mfma_f32_16x16x32_f16(af[3], bb, acc[3][br], 0, 0, 0); \
        } } while (0)

    STAGE(0, 0);
    for (int t = 0; t < NT; ++t) {
        if (t + 1 < NT) {
            STAGE(t + 1, (t + 1) & 1);
            asm volatile("s_waitcnt vmcnt(8)" ::: "memory");
        } else {
            asm volatile("s_waitcnt vmcnt(0)" ::: "memory");
        }
        __builtin_amdgcn_sched_barrier(0);
        __builtin_amdgcn_s_barrier();
        __builtin_amdgcn_sched_barrier(0);
        COMPUTE(t & 1);
        __builtin_amdgcn_sched_barrier(0);
        __builtin_amdgcn_s_barrier();
    }
#undef STAGE
#undef COMPUTE

    // fp16 partial stores. C/D: col = lane&15, row = (lane>>4)*4 + reg [m89/m91]
    _Float16* Pb = P + (size_t)sp * M * N;
    const int orow = bm + wm + lr * 4;
    const int ocol = bn + wn + lc;
    #pragma unroll
    for (int ar = 0; ar < 4; ++ar)
        #pragma unroll
        for (int br = 0; br < 4; ++br)
            #pragma unroll
            for (int r = 0; r < 4; ++r)
                Pb[(size_t)(orow + ar * 16 + r) * N + ocol + br * 16]
                    = (_Float16)acc[ar][br][r];

    // ---- fused finalize: last sp-block of this output tile sums + writes O ----
    __threadfence();                       // make this thread's partials L2-visible
    __syncthreads();                       // all 256 threads' stores fenced
    if (tid == 0)
        isWinner = (atomicAdd(&cnt[tileId], 1) == SPL - 1);
    __syncthreads();
    if (isWinner) {
        __threadfence();                   // acquire side
        const int r0 = tid >> 5;           // 0..7
        const int c0 = (tid & 31) * 4;     // 0..124
        #pragma unroll
        for (int rr = 0; rr < 16; ++rr) {
            const int row = bm + rr * 8 + r0;
            const int col = bn + c0;
            float a0 = 0.f, a1 = 0.f, a2 = 0.f, a3 = 0.f;
            #pragma unroll
            for (int s = 0; s < SPL; ++s) {
                half4 u = *(const half4*)(P + (size_t)s * M * N
                                            + (size_t)row * N + col);
                a0 += (float)u[0]; a1 += (float)u[1];
                a2 += (float)u[2]; a3 += (float)u[3];
            }
            const float4 sc = *(const float4*)(S + col);
            const float4 bb = *(const float4*)(Bi + col);
            float4 o4;
            o4.x = (float)(_Float16)((float)(_Float16)(a0 * sc.x) + bb.x);
            o4.y = (float)(_Float16)((float)(_Float16)(a1 * sc.y) + bb.y);
            o4.z = (float)(_Float16)((float)(_Float16)(a2 * sc.z) + bb.z);
            o4.w = (float)(_Float16)((float)(_Float16)(a3 * sc.w) + bb.w);
            *(float4*)(O + (size_t)row * N + col) = o4;
        }
    }
}

// correctness fallback if d_ws is too small
__global__ __launch_bounds__(256)
void fp6lin_small(const float* __restrict__ X, const float* __restrict__ W,
                  const float* __restrict__ S, const float* __restrict__ Bi,
                  float* __restrict__ O)
{
    const int n = (int)blockIdx.x;
    const int m = (int)threadIdx.x;
    float s = 0.f;
    for (int k = 0; k < K; ++k)
        s += (float)(_Float16)X[(size_t)m * K + k] * (float)(_Float16)W[(size_t)n * K + k];
    O[(size_t)m * N + n] = (float)(_Float16)((float)(_Float16)(s * S[n]) + Bi[n]);
}

extern "C" void kernel_launch(void* const* d_in, const int* in_sizes, int n_in,
                              void* d_out, int out_size, void* d_ws, size_t ws_size,
                              hipStream_t stream) {
    const float* x  = (const float*)d_in[0];
    const float* w  = (const float*)d_in[1];
    const float* s  = (const float*)d_in[2];
    const float* bi = (const float*)d_in[3];
    float* o = (float*)d_out;

    const size_t pbytes = (size_t)SPL * M * N * 2;   // 16 MB fp16 partials
    _Float16* P  = (_Float16*)d_ws;
    int* cnt     = (int*)((char*)d_ws + pbytes);     // 64 counters

    if (ws_size >= pbytes + 64 * sizeof(int)) {
        hipMemsetAsync(cnt, 0, 64 * sizeof(int), stream);
        gemm<<<dim3(512), dim3(256), 0, stream>>>(x, w, s, bi, o, P, cnt);
    } else {
        fp6lin_small<<<dim3(N), dim3(M), 0, stream>>>(x, w, s, bi, o);
    }
}

// Round 23
// 40.829 us; speedup vs baseline: 2.9781x; 2.9781x over previous
//
#include <hip/hip_runtime.h>
#include <hip/hip_fp16.h>

// out[m][n] = fp16( fp16( (sum_k x[m][k]*w6[n][k]) * scale[n] ) + bias[n] ), stored fp32
// v21: BARRIER-FREE wave-private pipeline. 1 wave/block, wave-tile 64x64, private
// LDS (A+W fp32, dbuf, 32KB). Zero s_barrier: per-wave counted vmcnt(16) is the only
// sync (FIFO: waiting leaves only tile t+1's 16 DMAs outstanding -> tile t landed).
// 4 blocks/CU all-resident -> request queue never drains (fixes the ~45% memory duty
// cycle of the barrier-lockstep v15/v18 at ~26us). SPL=4, fp16 partials, finalize.

typedef __attribute__((ext_vector_type(8))) _Float16 half8;
typedef __attribute__((ext_vector_type(2))) __fp16 fp16x2;   // cvt_pkrtz return type
typedef __attribute__((ext_vector_type(4))) float f32x4;

typedef const __attribute__((address_space(1))) void* gptr_t;
typedef __attribute__((address_space(3))) void* lptr_t;

constexpr int K = 4096, N = 4096, M = 256;
constexpr int BK = 32;
constexpr int SPL = 4;
constexpr int KSPL = K / SPL;     // 1024
constexpr int NT = KSPL / BK;     // 32 phases

__device__ __forceinline__ void gload16(const void* g, void* l) {
    __builtin_amdgcn_global_load_lds((gptr_t)g, (lptr_t)l, 16, 0, 0);
}

__device__ __forceinline__ half8 cvt8(float4 f0, float4 f1) {   // exact: fp16-exact data
    fp16x2 p0 = __builtin_amdgcn_cvt_pkrtz(f0.x, f0.y);
    fp16x2 p1 = __builtin_amdgcn_cvt_pkrtz(f0.z, f0.w);
    fp16x2 p2 = __builtin_amdgcn_cvt_pkrtz(f1.x, f1.y);
    fp16x2 p3 = __builtin_amdgcn_cvt_pkrtz(f1.z, f1.w);
    half8 h;
    h[0]=(_Float16)p0[0]; h[1]=(_Float16)p0[1];
    h[2]=(_Float16)p1[0]; h[3]=(_Float16)p1[1];
    h[4]=(_Float16)p2[0]; h[5]=(_Float16)p2[1];
    h[6]=(_Float16)p3[0]; h[7]=(_Float16)p3[1];
    return h;
}

__global__ __launch_bounds__(64, 1)
void gemm(const float* __restrict__ X,
          const float* __restrict__ W,
          _Float16* __restrict__ P)     // [SPL][M][N] fp16 partials
{
    __shared__ __align__(16) float LA[2][64 * BK];   // 2 x 8 KB, wave-private
    __shared__ __align__(16) float LB[2][64 * BK];   // 2 x 8 KB, wave-private

    const int l  = (int)threadIdx.x;    // one wave
    const int lc = l & 15;
    const int lr = l >> 4;

    // grid 1024 = mb(4) x sp(4) x nbl(8) x xcd(8). Per XCD: 8 N-panels (512 W rows,
    // HBM once — the 16 sharers (mb x sp) of each panel are co-resident on that XCD).
    const int bid = (int)blockIdx.x;
    const int xcd = bid & 7;
    const int i   = bid >> 3;           // 0..127
    const int mb  = i & 3;
    const int sp  = (i >> 2) & 3;
    const int nbl = i >> 4;             // 0..7
    const int bm  = mb * 64;
    const int bn  = (xcd * 8 + nbl) * 64;
    const int kb  = sp * KSPL;

    // DMA staging map: per op-tile 8 insts of 1KB (8 rows x 128B). lane l -> row l>>3,
    // 16B chunk (l&7); global source chunk pre-XOR-swizzled with row&7 (== l>>3).
    const int srow = l >> 3;
    const int sch  = ((l & 7) ^ (l >> 3)) * 4;       // floats
    const float* ax = X + (size_t)(bm + srow) * K + kb + sch;
    const float* wx = W + (size_t)(bn + srow) * K + kb + sch;

#define STAGE(t, bf) do {                                                \
        _Pragma("unroll")                                                \
        for (int s = 0; s < 8; ++s) {                                    \
            gload16(ax + (size_t)(s * 8) * K + (size_t)(t) * BK,         \
                    &LA[bf][s * 256]);                                   \
            gload16(wx + (size_t)(s * 8) * K + (size_t)(t) * BK,         \
                    &LB[bf][s * 256]);                                   \
        } } while (0)   // exactly 16 vmem ops per tile

    // frag read offsets (row = 16q+lc -> row&7 == lc&7; fp32 chunk pair {2lr,2lr+1}
    // stored XOR (lc&7))
    const int sz0 = (((lr << 1))     ^ (lc & 7)) << 2;   // floats
    const int sz1 = (((lr << 1) | 1) ^ (lc & 7)) << 2;

    f32x4 acc[4][4];
    #pragma unroll
    for (int a = 0; a < 4; ++a)
        #pragma unroll
        for (int b = 0; b < 4; ++b)
            acc[a][b] = (f32x4){0.f, 0.f, 0.f, 0.f};

#define COMPUTE(bf) do {                                                 \
        half8 af[4];                                                     \
        _Pragma("unroll")                                                \
        for (int ar = 0; ar < 4; ++ar) {                                 \
            const float* pa = &LA[bf][(ar * 16 + lc) * BK];              \
            af[ar] = cvt8(*(const float4*)(pa + sz0),                    \
                          *(const float4*)(pa + sz1));                   \
        }                                                                \
        _Pragma("unroll")                                                \
        for (int br = 0; br < 4; ++br) {                                 \
            const float* pw = &LB[bf][(br * 16 + lc) * BK];              \
            half8 bb = cvt8(*(const float4*)(pw + sz0),                  \
                            *(const float4*)(pw + sz1));                 \
            acc[0][br] = __builtin_amdgcn_mfma_f32_16x16x32_f16(af[0], bb, acc[0][br], 0, 0, 0); \
            acc[1][br] = __builtin_amdgcn_mfma_f32_16x16x32_f16(af[1], bb, acc[1][br], 0, 0, 0); \
            acc[2][br] = __builtin_amdgcn_mfma_f32_16x16x32_f16(af[2], bb, acc[2][br], 0, 0, 0); \
            acc[3][br] = __builtin_amdgcn_mfma_f32_16x16x32_f16(af[3], bb, acc[3][br], 0, 0, 0); \
        } } while (0)

    STAGE(0, 0);                         // prime
    for (int t = 0; t < NT; ++t) {
        if (t + 1 < NT) {
            STAGE(t + 1, (t + 1) & 1);   // keep 16 in flight
            __builtin_amdgcn_sched_barrier(0);
            asm volatile("s_waitcnt vmcnt(16)" ::: "memory");   // tile t landed
        } else {
            asm volatile("s_waitcnt vmcnt(0)" ::: "memory");
        }
        __builtin_amdgcn_sched_barrier(0);
        COMPUTE(t & 1);                  // wave-private LDS: no barrier needed
        __builtin_amdgcn_sched_barrier(0);
    }
#undef STAGE
#undef COMPUTE

    // fp16 partial stores. C/D: col = lane&15, row = (lane>>4)*4 + reg [m89/m91]
    _Float16* Pb = P + (size_t)sp * M * N;
    const int orow = bm + lr * 4;
    const int ocol = bn + lc;
    #pragma unroll
    for (int ar = 0; ar < 4; ++ar)
        #pragma unroll
        for (int br = 0; br < 4; ++br)
            #pragma unroll
            for (int r = 0; r < 4; ++r)
                Pb[(size_t)(orow + ar * 16 + r) * N + ocol + br * 16]
                    = (_Float16)acc[ar][br][r];
}

// O = fp32( fp16( fp16( (sum of SPL fp16 partials) * scale[n] ) + bias[n] ) )
__global__ __launch_bounds__(256)
void finalize(const _Float16* __restrict__ P,
              const float* __restrict__ S,
              const float* __restrict__ Bi,
              float* __restrict__ O)
{
    const size_t i = ((size_t)blockIdx.x * 256 + threadIdx.x) * 8;
    const int n = (int)(i & (N - 1));
    float acc[8] = {0.f, 0.f, 0.f, 0.f, 0.f, 0.f, 0.f, 0.f};
    #pragma unroll
    for (int s = 0; s < SPL; ++s) {
        half8 u = *(const half8*)(P + (size_t)s * M * N + i);
        #pragma unroll
        for (int e = 0; e < 8; ++e) acc[e] += (float)u[e];
    }
    float4 sc0 = *(const float4*)(S + n);
    float4 sc1 = *(const float4*)(S + n + 4);
    float4 bb0 = *(const float4*)(Bi + n);
    float4 bb1 = *(const float4*)(Bi + n + 4);
    float sc[8] = {sc0.x, sc0.y, sc0.z, sc0.w, sc1.x, sc1.y, sc1.z, sc1.w};
    float bb[8] = {bb0.x, bb0.y, bb0.z, bb0.w, bb1.x, bb1.y, bb1.z, bb1.w};
    float out[8];
    #pragma unroll
    for (int e = 0; e < 8; ++e)
        out[e] = (float)(_Float16)((float)(_Float16)(acc[e] * sc[e]) + bb[e]);
    *(float4*)(O + i)     = (float4){out[0], out[1], out[2], out[3]};
    *(float4*)(O + i + 4) = (float4){out[4], out[5], out[6], out[7]};
}

// correctness fallback if d_ws is too small
__global__ __launch_bounds__(256)
void fp6lin_small(const float* __restrict__ X, const float* __restrict__ W,
                  const float* __restrict__ S, const float* __restrict__ Bi,
                  float* __restrict__ O)
{
    const int n = (int)blockIdx.x;
    const int m = (int)threadIdx.x;
    float s = 0.f;
    for (int k = 0; k < K; ++k)
        s += (float)(_Float16)X[(size_t)m * K + k] * (float)(_Float16)W[(size_t)n * K + k];
    O[(size_t)m * N + n] = (float)(_Float16)((float)(_Float16)(s * S[n]) + Bi[n]);
}

extern "C" void kernel_launch(void* const* d_in, const int* in_sizes, int n_in,
                              void* d_out, int out_size, void* d_ws, size_t ws_size,
                              hipStream_t stream) {
    const float* x  = (const float*)d_in[0];
    const float* w  = (const float*)d_in[1];
    const float* s  = (const float*)d_in[2];
    const float* bi = (const float*)d_in[3];
    float* o = (float*)d_out;

    const size_t pbytes = (size_t)SPL * M * N * 2;   // 8 MB fp16 partials
    _Float16* P = (_Float16*)d_ws;

    if (ws_size >= pbytes) {
        gemm<<<dim3(1024), dim3(64), 0, stream>>>(x, w, P);
        finalize<<<dim3(M * N / 8 / 256), dim3(256), 0, stream>>>(P, s, bi, o);
    } else {
        fp6lin_small<<<dim3(N), dim3(M), 0, stream>>>(x, w, s, bi, o);
    }
}

// Round 24
// 33.165 us; speedup vs baseline: 3.6663x; 1.2311x over previous
//
#include <hip/hip_runtime.h>
#include <hip/hip_fp16.h>

// out[m][n] = fp16( fp16( (sum_k x[m][k]*w6[n][k]) * scale[n] ) + bias[n] ), stored fp32
// v22: fp16-in-LDS. Reg-staged: GLOAD(t+2)->regs early; COMPUTE(t) (8 ds_read_b128 +
// 16 MFMA per wave, m97 density, no cvt in frag path); counted vmcnt(8); cvt_pkrtz +
// ds_write_b64 into buf^1; lgkmcnt(0) + ONE raw barrier per phase. Asm fences stop
// the load-sinking that killed r6/r9 reg-staging. fp16 [128][32] LDS needs no swizzle
// (row = 64B). 128x128 tile, 64x64 wave tile, BK=32, SPL=8, fp16 partials + finalize.

typedef __attribute__((ext_vector_type(8))) _Float16 half8;
typedef __attribute__((ext_vector_type(4))) _Float16 half4;
typedef __attribute__((ext_vector_type(2))) __fp16 fp16x2;   // cvt_pkrtz return type
typedef __attribute__((ext_vector_type(4))) float f32x4;

constexpr int K = 4096, N = 4096, M = 256;
constexpr int BM = 128, BN = 128, BK = 32;
constexpr int SPL = 8;
constexpr int KSPL = K / SPL;     // 512
constexpr int NT = KSPL / BK;     // 16 phases

__device__ __forceinline__ half4 cvt4(float4 f) {   // exact: fp16-exact data
    fp16x2 p0 = __builtin_amdgcn_cvt_pkrtz(f.x, f.y);
    fp16x2 p1 = __builtin_amdgcn_cvt_pkrtz(f.z, f.w);
    half4 h;
    h[0]=(_Float16)p0[0]; h[1]=(_Float16)p0[1];
    h[2]=(_Float16)p1[0]; h[3]=(_Float16)p1[1];
    return h;
}

__global__ __launch_bounds__(256, 2)
void gemm(const float* __restrict__ X,
          const float* __restrict__ W,
          _Float16* __restrict__ P)     // [SPL][M][N] fp16 partials
{
    __shared__ __align__(16) _Float16 LA[2][BM * BK];   // 2 x 8 KB fp16
    __shared__ __align__(16) _Float16 LB[2][BN * BK];   // 2 x 8 KB fp16

    const int tid = (int)threadIdx.x;
    const int l   = tid & 63;
    const int wv  = tid >> 6;           // 4 waves: 2(M) x 2(N), wave tile 64x64
    const int lc  = l & 15;
    const int lr  = l >> 4;
    const int wm  = (wv & 1) * 64;
    const int wn  = (wv >> 1) * 64;

    // XCD map (v18): per XCD 4 N-tiles; mb fastest; sp in same-XCD bits.
    const int bid = (int)blockIdx.x;
    const int xcd = bid & 7;
    const int i   = bid >> 3;           // 0..63
    const int mb  = i & 1;
    const int sp  = (i >> 1) & 7;
    const int nbl = i >> 4;             // 0..3
    const int bm  = mb * BM;
    const int bn  = (xcd * 4 + nbl) * BN;
    const int kb  = sp * KSPL;

    // ---- staging map: wave wv covers rows [wv*32, wv*32+32) of each op tile.
    //      inst j: rows wv*32+8j+(l>>3), 16B fp32 chunk l&7 (coalesced 1KB/inst).
    const int srow = wv * 32 + (l >> 3);             // +8 per inst
    const int scol = (l & 7) * 4;                    // floats
    const float* ax0 = X + (size_t)(bm + srow)      * K + kb + scol;
    const float* ax1 = X + (size_t)(bm + srow + 8)  * K + kb + scol;
    const float* ax2 = X + (size_t)(bm + srow + 16) * K + kb + scol;
    const float* ax3 = X + (size_t)(bm + srow + 24) * K + kb + scol;
    const float* wx0 = W + (size_t)(bn + srow)      * K + kb + scol;
    const float* wx1 = W + (size_t)(bn + srow + 8)  * K + kb + scol;
    const float* wx2 = W + (size_t)(bn + srow + 16) * K + kb + scol;
    const float* wx3 = W + (size_t)(bn + srow + 24) * K + kb + scol;
    // LDS write half-index for inst j: (srow + 8j)*BK + 4*(l&7)
    const int wr0 = srow * BK + (l & 7) * 4;         // + 8*BK per inst

    // named register slots (rule 20): 2 slots x (4 A + 4 W) float4
    float4 s0a0, s0a1, s0a2, s0a3, s0w0, s0w1, s0w2, s0w3;
    float4 s1a0, s1a1, s1a2, s1a3, s1w0, s1w1, s1w2, s1w3;

#define GLOAD0(t) do { const size_t o = (size_t)(t) * BK;               \
        s0a0 = *(const float4*)(ax0 + o); s0a1 = *(const float4*)(ax1 + o); \
        s0a2 = *(const float4*)(ax2 + o); s0a3 = *(const float4*)(ax3 + o); \
        s0w0 = *(const float4*)(wx0 + o); s0w1 = *(const float4*)(wx1 + o); \
        s0w2 = *(const float4*)(wx2 + o); s0w3 = *(const float4*)(wx3 + o); } while (0)
#define GLOAD1(t) do { const size_t o = (size_t)(t) * BK;               \
        s1a0 = *(const float4*)(ax0 + o); s1a1 = *(const float4*)(ax1 + o); \
        s1a2 = *(const float4*)(ax2 + o); s1a3 = *(const float4*)(ax3 + o); \
        s1w0 = *(const float4*)(wx0 + o); s1w1 = *(const float4*)(wx1 + o); \
        s1w2 = *(const float4*)(wx2 + o); s1w3 = *(const float4*)(wx3 + o); } while (0)
#define CVTW0(bf) do {                                                  \
        *(half4*)(&LA[bf][wr0])          = cvt4(s0a0);                  \
        *(half4*)(&LA[bf][wr0 + 8*BK])   = cvt4(s0a1);                  \
        *(half4*)(&LA[bf][wr0 + 16*BK])  = cvt4(s0a2);                  \
        *(half4*)(&LA[bf][wr0 + 24*BK])  = cvt4(s0a3);                  \
        *(half4*)(&LB[bf][wr0])          = cvt4(s0w0);                  \
        *(half4*)(&LB[bf][wr0 + 8*BK])   = cvt4(s0w1);                  \
        *(half4*)(&LB[bf][wr0 + 16*BK])  = cvt4(s0w2);                  \
        *(half4*)(&LB[bf][wr0 + 24*BK])  = cvt4(s0w3); } while (0)
#define CVTW1(bf) do {                                                  \
        *(half4*)(&LA[bf][wr0])          = cvt4(s1a0);                  \
        *(half4*)(&LA[bf][wr0 + 8*BK])   = cvt4(s1a1);                  \
        *(half4*)(&LA[bf][wr0 + 16*BK])  = cvt4(s1a2);                  \
        *(half4*)(&LA[bf][wr0 + 24*BK])  = cvt4(s1a3);                  \
        *(half4*)(&LB[bf][wr0])          = cvt4(s1w0);                  \
        *(half4*)(&LB[bf][wr0 + 8*BK])   = cvt4(s1w1);                  \
        *(half4*)(&LB[bf][wr0 + 16*BK])  = cvt4(s1w2);                  \
        *(half4*)(&LB[bf][wr0 + 24*BK])  = cvt4(s1w3); } while (0)

    f32x4 acc[4][4];
    #pragma unroll
    for (int a = 0; a < 4; ++a)
        #pragma unroll
        for (int b = 0; b < 4; ++b)
            acc[a][b] = (f32x4){0.f, 0.f, 0.f, 0.f};

    // frag offsets: m97-style direct half8 (16B contiguous at k = lr*8)
#define COMPUTE(bf) do {                                                \
        half8 af[4], wf[4];                                             \
        _Pragma("unroll")                                               \
        for (int ar = 0; ar < 4; ++ar)                                  \
            af[ar] = *(const half8*)(&LA[bf][(wm + ar * 16 + lc) * BK + lr * 8]); \
        _Pragma("unroll")                                               \
        for (int br = 0; br < 4; ++br)                                  \
            wf[br] = *(const half8*)(&LB[bf][(wn + br * 16 + lc) * BK + lr * 8]); \
        _Pragma("unroll")                                               \
        for (int ar = 0; ar < 4; ++ar)                                  \
            _Pragma("unroll")                                           \
            for (int br = 0; br < 4; ++br)                              \
                acc[ar][br] = __builtin_amdgcn_mfma_f32_16x16x32_f16(   \
                    af[ar], wf[br], acc[ar][br], 0, 0, 0); } while (0)

    // prologue: tile0 -> slot0, tile1 -> slot1; cvt tile0 into buf0
    GLOAD0(0);
    GLOAD1(1);
    asm volatile("s_waitcnt vmcnt(8)" ::: "memory");   // tile0's 8 landed
    CVTW0(0);
    asm volatile("s_waitcnt lgkmcnt(0)" ::: "memory");
    __builtin_amdgcn_s_barrier();

    for (int t = 0; t < NT; ++t) {
        // issue tile t+2 into the slot just freed (slot t&1)
        const int tn = (t + 2 < NT) ? t + 2 : NT - 1;   // clamped (redundant at tail)
        if (t & 1) GLOAD1(tn); else GLOAD0(tn);
        __builtin_amdgcn_sched_barrier(0);
        COMPUTE(t & 1);
        asm volatile("s_waitcnt vmcnt(8)" ::: "memory");   // tile t+1 landed
        __builtin_amdgcn_sched_barrier(0);
        if (t & 1) CVTW0((t + 1) & 1); else CVTW1((t + 1) & 1);
        asm volatile("s_waitcnt lgkmcnt(0)" ::: "memory"); // ds_writes done
        __builtin_amdgcn_s_barrier();                       // ONE barrier per phase
    }
#undef GLOAD0
#undef GLOAD1
#undef CVTW0
#undef CVTW1
#undef COMPUTE

    // fp16 partial stores. C/D: col = lane&15, row = (lane>>4)*4 + reg [m89/m91]
    _Float16* Pb = P + (size_t)sp * M * N;
    const int orow = bm + wm + lr * 4;
    const int ocol = bn + wn + lc;
    #pragma unroll
    for (int ar = 0; ar < 4; ++ar)
        #pragma unroll
        for (int br = 0; br < 4; ++br)
            #pragma unroll
            for (int r = 0; r < 4; ++r)
                Pb[(size_t)(orow + ar * 16 + r) * N + ocol + br * 16]
                    = (_Float16)acc[ar][br][r];
}

// O = fp32( fp16( fp16( (sum of SPL fp16 partials) * scale[n] ) + bias[n] ) )
__global__ __launch_bounds__(256)
void finalize(const _Float16* __restrict__ P,
              const float* __restrict__ S,
              const float* __restrict__ Bi,
              float* __restrict__ O)
{
    const size_t i = ((size_t)blockIdx.x * 256 + threadIdx.x) * 8;
    const int n = (int)(i & (N - 1));
    float acc[8] = {0.f, 0.f, 0.f, 0.f, 0.f, 0.f, 0.f, 0.f};
    #pragma unroll
    for (int s = 0; s < SPL; ++s) {
        half8 u = *(const half8*)(P + (size_t)s * M * N + i);
        #pragma unroll
        for (int e = 0; e < 8; ++e) acc[e] += (float)u[e];
    }
    float4 sc0 = *(const float4*)(S + n);
    float4 sc1 = *(const float4*)(S + n + 4);
    float4 bb0 = *(const float4*)(Bi + n);
    float4 bb1 = *(const float4*)(Bi + n + 4);
    float sc[8] = {sc0.x, sc0.y, sc0.z, sc0.w, sc1.x, sc1.y, sc1.z, sc1.w};
    float bb[8] = {bb0.x, bb0.y, bb0.z, bb0.w, bb1.x, bb1.y, bb1.z, bb1.w};
    float out[8];
    #pragma unroll
    for (int e = 0; e < 8; ++e)
        out[e] = (float)(_Float16)((float)(_Float16)(acc[e] * sc[e]) + bb[e]);
    *(float4*)(O + i)     = (float4){out[0], out[1], out[2], out[3]};
    *(float4*)(O + i + 4) = (float4){out[4], out[5], out[6], out[7]};
}

// correctness fallback if d_ws is too small
__global__ __launch_bounds__(256)
void fp6lin_small(const float* __restrict__ X, const float* __restrict__ W,
                  const float* __restrict__ S, const float* __restrict__ Bi,
                  float* __restrict__ O)
{
    const int n = (int)blockIdx.x;
    const int m = (int)threadIdx.x;
    float s = 0.f;
    for (int k = 0; k < K; ++k)
        s += (float)(_Float16)X[(size_t)m * K + k] * (float)(_Float16)W[(size_t)n * K + k];
    O[(size_t)m * N + n] = (float)(_Float16)((float)(_Float16)(s * S[n]) + Bi[n]);
}

extern "C" void kernel_launch(void* const* d_in, const int* in_sizes, int n_in,
                              void* d_out, int out_size, void* d_ws, size_t ws_size,
                              hipStream_t stream) {
    const float* x  = (const float*)d_in[0];
    const float* w  = (const float*)d_in[1];
    const float* s  = (const float*)d_in[2];
    const float* bi = (const float*)d_in[3];
    float* o = (float*)d_out;

    const size_t pbytes = (size_t)SPL * M * N * 2;   // 16 MB fp16 partials
    _Float16* P = (_Float16*)d_ws;

    if (ws_size >= pbytes) {
        gemm<<<dim3(512), dim3(256), 0, stream>>>(x, w, P);
        finalize<<<dim3(M * N / 8 / 256), dim3(256), 0, stream>>>(P, s, bi, o);
    } else {
        fp6lin_small<<<dim3(N), dim3(M), 0, stream>>>(x, w, s, bi, o);
    }
}

// Round 25
// 30.546 us; speedup vs baseline: 3.9807x; 1.0857x over previous
//
#include <hip/hip_runtime.h>
#include <hip/hip_fp16.h>

// out[m][n] = fp16( fp16( (sum_k x[m][k]*w6[n][k]) * scale[n] ) + bias[n] ), stored fp32
// v23: TLP x fp16-LDS x counted-wait. Tile 128x64, BK=32, 4 waves (wave-tile 64x32,
// acc=32 VGPR), grid 1024 -> 4 blocks/CU (32 waves/CU): when one block waits on vmem,
// three others issue -> fills the exposed latency that capped v18/v22 at ~3 TB/s.
// Reg-staged fp32->fp16 cvt (asm-fenced, 1-deep), ONE raw barrier/phase, SPL=8,
// fp16 partials + finalize.

typedef __attribute__((ext_vector_type(8))) _Float16 half8;
typedef __attribute__((ext_vector_type(4))) _Float16 half4;
typedef __attribute__((ext_vector_type(2))) __fp16 fp16x2;   // cvt_pkrtz return type
typedef __attribute__((ext_vector_type(4))) float f32x4;

constexpr int K = 4096, N = 4096, M = 256;
constexpr int BM = 128, BN = 64, BK = 32;
constexpr int SPL = 8;
constexpr int KSPL = K / SPL;     // 512
constexpr int NT = KSPL / BK;     // 16 phases

__device__ __forceinline__ half4 cvt4(float4 f) {   // exact: fp16-exact data
    fp16x2 p0 = __builtin_amdgcn_cvt_pkrtz(f.x, f.y);
    fp16x2 p1 = __builtin_amdgcn_cvt_pkrtz(f.z, f.w);
    half4 h;
    h[0]=(_Float16)p0[0]; h[1]=(_Float16)p0[1];
    h[2]=(_Float16)p1[0]; h[3]=(_Float16)p1[1];
    return h;
}

__global__ __launch_bounds__(256, 4)
void gemm(const float* __restrict__ X,
          const float* __restrict__ W,
          _Float16* __restrict__ P)     // [SPL][M][N] fp16 partials
{
    __shared__ __align__(16) _Float16 LA[2][BM * BK];   // 2 x 8 KB fp16
    __shared__ __align__(16) _Float16 LB[2][BN * BK];   // 2 x 4 KB fp16

    const int tid = (int)threadIdx.x;
    const int l   = tid & 63;
    const int wv  = tid >> 6;           // 4 waves: 2(M) x 2(N), wave tile 64x32
    const int lc  = l & 15;
    const int lr  = l >> 4;
    const int wm  = (wv & 1) * 64;
    const int wn  = (wv >> 1) * 32;

    // grid 1024 = xcd(8) x [mb(2) x sp(8) x nbl(8)]. Per XCD: 8 N-panels x 64 rows
    // = 512 W rows (8 MB) HBM-read once; the 2 mb-sharers of each panel co-resident.
    const int bid = (int)blockIdx.x;
    const int xcd = bid & 7;
    const int i   = bid >> 3;           // 0..127
    const int mb  = i & 1;
    const int sp  = (i >> 1) & 7;
    const int nbl = i >> 4;             // 0..7
    const int bm  = mb * BM;
    const int bn  = (xcd * 8 + nbl) * BN;
    const int kb  = sp * KSPL;

    // ---- staging maps (fp32 global -> regs; coalesced 1KB/inst) ----
    // A (128x32): 4 insts/wave; inst j rows wv*32+8j+(l>>3), cols (l&7)*4
    const int arow = wv * 32 + (l >> 3);
    // W (64x32): 2 insts/wave; inst j rows wv*16+8j+(l>>3)
    const int wrow = wv * 16 + (l >> 3);
    const int scol = (l & 7) * 4;
    const float* ax0 = X + (size_t)(bm + arow)      * K + kb + scol;
    const float* ax1 = X + (size_t)(bm + arow + 8)  * K + kb + scol;
    const float* ax2 = X + (size_t)(bm + arow + 16) * K + kb + scol;
    const float* ax3 = X + (size_t)(bm + arow + 24) * K + kb + scol;
    const float* wx0 = W + (size_t)(bn + wrow)      * K + kb + scol;
    const float* wx1 = W + (size_t)(bn + wrow + 8)  * K + kb + scol;
    // LDS half-index write bases
    const int awr = arow * BK + (l & 7) * 4;
    const int wwr = wrow * BK + (l & 7) * 4;

    // named register slots (rule 20): 1 tile = 6 float4
    float4 sa0, sa1, sa2, sa3, sw0, sw1;

#define GLOAD(t) do { const size_t o = (size_t)(t) * BK;                \
        sa0 = *(const float4*)(ax0 + o); sa1 = *(const float4*)(ax1 + o); \
        sa2 = *(const float4*)(ax2 + o); sa3 = *(const float4*)(ax3 + o); \
        sw0 = *(const float4*)(wx0 + o); sw1 = *(const float4*)(wx1 + o); } while (0)
#define CVTW(bf) do {                                                   \
        *(half4*)(&LA[bf][awr])         = cvt4(sa0);                    \
        *(half4*)(&LA[bf][awr + 8*BK])  = cvt4(sa1);                    \
        *(half4*)(&LA[bf][awr + 16*BK]) = cvt4(sa2);                    \
        *(half4*)(&LA[bf][awr + 24*BK]) = cvt4(sa3);                    \
        *(half4*)(&LB[bf][wwr])         = cvt4(sw0);                    \
        *(half4*)(&LB[bf][wwr + 8*BK])  = cvt4(sw1); } while (0)

    f32x4 acc[4][2];
    #pragma unroll
    for (int a = 0; a < 4; ++a)
        #pragma unroll
        for (int b = 0; b < 2; ++b)
            acc[a][b] = (f32x4){0.f, 0.f, 0.f, 0.f};

    // frags: direct half8 at [row][lr*8] (16B contiguous, m97 style)
#define COMPUTE(bf) do {                                                \
        half8 af[4], wf[2];                                             \
        _Pragma("unroll")                                               \
        for (int ar = 0; ar < 4; ++ar)                                  \
            af[ar] = *(const half8*)(&LA[bf][(wm + ar * 16 + lc) * BK + lr * 8]); \
        _Pragma("unroll")                                               \
        for (int br = 0; br < 2; ++br)                                  \
            wf[br] = *(const half8*)(&LB[bf][(wn + br * 16 + lc) * BK + lr * 8]); \
        _Pragma("unroll")                                               \
        for (int ar = 0; ar < 4; ++ar)                                  \
            _Pragma("unroll")                                           \
            for (int br = 0; br < 2; ++br)                              \
                acc[ar][br] = __builtin_amdgcn_mfma_f32_16x16x32_f16(   \
                    af[ar], wf[br], acc[ar][br], 0, 0, 0); } while (0)

    // prologue: tile 0 -> buf 0
    GLOAD(0);
    asm volatile("s_waitcnt vmcnt(0)" ::: "memory");
    CVTW(0);
    asm volatile("s_waitcnt lgkmcnt(0)" ::: "memory");
    __builtin_amdgcn_s_barrier();

    for (int t = 0; t < NT; ++t) {
        if (t + 1 < NT) {
            GLOAD(t + 1);                       // issue early; lat hidden by COMPUTE+TLP
            __builtin_amdgcn_sched_barrier(0);
        }
        COMPUTE(t & 1);
        if (t + 1 < NT) {
            asm volatile("s_waitcnt vmcnt(0)" ::: "memory");   // only our 6 outstanding
            __builtin_amdgcn_sched_barrier(0);
            CVTW((t + 1) & 1);
            asm volatile("s_waitcnt lgkmcnt(0)" ::: "memory");
            __builtin_amdgcn_s_barrier();       // ONE barrier per phase
        }
    }
#undef GLOAD
#undef CVTW
#undef COMPUTE

    // fp16 partial stores. C/D: col = lane&15, row = (lane>>4)*4 + reg [m89/m91]
    _Float16* Pb = P + (size_t)sp * M * N;
    const int orow = bm + wm + lr * 4;
    const int ocol = bn + wn + lc;
    #pragma unroll
    for (int ar = 0; ar < 4; ++ar)
        #pragma unroll
        for (int br = 0; br < 2; ++br)
            #pragma unroll
            for (int r = 0; r < 4; ++r)
                Pb[(size_t)(orow + ar * 16 + r) * N + ocol + br * 16]
                    = (_Float16)acc[ar][br][r];
}

// O = fp32( fp16( fp16( (sum of SPL fp16 partials) * scale[n] ) + bias[n] ) )
__global__ __launch_bounds__(256)
void finalize(const _Float16* __restrict__ P,
              const float* __restrict__ S,
              const float* __restrict__ Bi,
              float* __restrict__ O)
{
    const size_t i = ((size_t)blockIdx.x * 256 + threadIdx.x) * 8;
    const int n = (int)(i & (N - 1));
    float acc[8] = {0.f, 0.f, 0.f, 0.f, 0.f, 0.f, 0.f, 0.f};
    #pragma unroll
    for (int s = 0; s < SPL; ++s) {
        half8 u = *(const half8*)(P + (size_t)s * M * N + i);
        #pragma unroll
        for (int e = 0; e < 8; ++e) acc[e] += (float)u[e];
    }
    float4 sc0 = *(const float4*)(S + n);
    float4 sc1 = *(const float4*)(S + n + 4);
    float4 bb0 = *(const float4*)(Bi + n);
    float4 bb1 = *(const float4*)(Bi + n + 4);
    float sc[8] = {sc0.x, sc0.y, sc0.z, sc0.w, sc1.x, sc1.y, sc1.z, sc1.w};
    float bb[8] = {bb0.x, bb0.y, bb0.z, bb0.w, bb1.x, bb1.y, bb1.z, bb1.w};
    float out[8];
    #pragma unroll
    for (int e = 0; e < 8; ++e)
        out[e] = (float)(_Float16)((float)(_Float16)(acc[e] * sc[e]) + bb[e]);
    *(float4*)(O + i)     = (float4){out[0], out[1], out[2], out[3]};
    *(float4*)(O + i + 4) = (float4){out[4], out[5], out[6], out[7]};
}

// correctness fallback if d_ws is too small
__global__ __launch_bounds__(256)
void fp6lin_small(const float* __restrict__ X, const float* __restrict__ W,
                  const float* __restrict__ S, const float* __restrict__ Bi,
                  float* __restrict__ O)
{
    const int n = (int)blockIdx.x;
    const int m = (int)threadIdx.x;
    float s = 0.f;
    for (int k = 0; k < K; ++k)
        s += (float)(_Float16)X[(size_t)m * K + k] * (float)(_Float16)W[(size_t)n * K + k];
    O[(size_t)m * N + n] = (float)(_Float16)((float)(_Float16)(s * S[n]) + Bi[n]);
}

extern "C" void kernel_launch(void* const* d_in, const int* in_sizes, int n_in,
                              void* d_out, int out_size, void* d_ws, size_t ws_size,
                              hipStream_t stream) {
    const float* x  = (const float*)d_in[0];
    const float* w  = (const float*)d_in[1];
    const float* s  = (const float*)d_in[2];
    const float* bi = (const float*)d_in[3];
    float* o = (float*)d_out;

    const size_t pbytes = (size_t)SPL * M * N * 2;   // 16 MB fp16 partials
    _Float16* P = (_Float16*)d_ws;

    if (ws_size >= pbytes) {
        gemm<<<dim3(1024), dim3(256), 0, stream>>>(x, w, P);
        finalize<<<dim3(M * N / 8 / 256), dim3(256), 0, stream>>>(P, s, bi, o);
    } else {
        fp6lin_small<<<dim3(N), dim3(M), 0, stream>>>(x, w, s, bi, o);
    }
}